// Round 1
// baseline (42.434 us; speedup 1.0000x reference)
//
#include <hip/hip_runtime.h>

#define Bt 32768
#define Dt 64
#define St 16
#define Ht 128
#define At 17

typedef __attribute__((ext_vector_type(8))) short bf16x8;
typedef __attribute__((ext_vector_type(4))) float f32x4;
typedef __attribute__((ext_vector_type(4))) unsigned short us4;

// ---- workspace layout (bytes) ----
#define CNT_OFF   0          // int[16]
#define PERM_OFF  128        // u16 [S][B]  (1 MiB)
#define WB_OFF    1049600    // bf16 swizzled weight images (16B aligned)
// per-skill weight image offsets (LDS-ready, XOR-swizzled)
#define OA1 0        // Wa1: n=128 rows, 128B/row (K=64)   -> 16384B
#define OA2 16384    // Wa2: n=128 rows, 256B/row (K=128)  -> 32768B
#define OA3 49152    // Wa3: n=32  rows, 256B/row (K=128)  ->  8192B
#define OC1 57344    // Wc1                                -> 16384B
#define OC2 73728    // Wc2                                -> 32768B
#define SKB 106496   // per-skill stride

__device__ __forceinline__ unsigned short f2bf(float f) {
  union { float f; unsigned u; } v; v.f = f;
  unsigned r = v.u + 0x7FFFu + ((v.u >> 16) & 1u);  // RNE
  return (unsigned short)(r >> 16);
}

__device__ __forceinline__ float fast_tanh(float x) {
  float t = __expf(2.0f * x);                 // inf-safe: t=inf -> 1, t=0 -> -1
  return 1.0f - __fdividef(2.0f, t + 1.0f);
}

__device__ __forceinline__ void ldsload16(const char* g, char* l) {
  __builtin_amdgcn_global_load_lds(
      (const __attribute__((address_space(1))) unsigned int*)g,
      (__attribute__((address_space(3))) unsigned int*)l, 16, 0, 0);
}

// stage `bytes` from pre-swizzled global image into LDS, linear copy.
// dest = (wave-uniform lds base) + lane*16 ; src per-lane.
__device__ __forceinline__ void stageW(const char* g, char* lds, int bytes,
                                       int wave, int lane) {
  for (int c = wave * 1024; c < bytes; c += 4096)
    ldsload16(g + c + lane * 16, lds + c);
}

__device__ __forceinline__ f32x4 MFMA(bf16x8 a, bf16x8 b, f32x4 c) {
  return __builtin_amdgcn_mfma_f32_16x16x32_bf16(a, b, c, 0, 0, 0);
}

// ---------- phase 1: bucket rows by skill ----------
__global__ __launch_bounds__(256) void k_bucket(const int* __restrict__ sid,
                                                unsigned short* __restrict__ perm,
                                                int* __restrict__ cnt) {
  __shared__ int lc[St], lb[St];
  const int tid = threadIdx.x;
  const int b = blockIdx.x * 256 + tid;   // B % 256 == 0
  if (tid < St) lc[tid] = 0;
  __syncthreads();
  const int s = sid[b];
  const int p = atomicAdd(&lc[s], 1);
  __syncthreads();
  if (tid < St) lb[tid] = atomicAdd(&cnt[tid], lc[tid]);
  __syncthreads();
  perm[s * Bt + lb[s] + p] = (unsigned short)b;
}

// ---------- phase 2: fp32 -> bf16, transpose to [n][k], XOR-swizzle ----------
// image byte position q within a matrix: n = q>>log2(SB), r = q&(SB-1),
// kbyte = r ^ ((n&7)<<4).  Writes are fully coalesced 8B/thread.
__global__ __launch_bounds__(256) void k_prep(const float* __restrict__ Wa1,
                                              const float* __restrict__ Wa2,
                                              const float* __restrict__ Wa3,
                                              const float* __restrict__ Wc1,
                                              const float* __restrict__ Wc2,
                                              char* __restrict__ G) {
  const int s = blockIdx.y;
  const int q = (blockIdx.x * 256 + threadIdx.x) * 8;
  const float* src; int mb, sbl, ncols;
  if (q < OA2)      { mb = OA1; src = Wa1 + s * Dt * Ht; sbl = 7; ncols = Ht; }
  else if (q < OA3) { mb = OA2; src = Wa2 + s * Ht * Ht; sbl = 8; ncols = Ht; }
  else if (q < OC1) { mb = OA3; src = Wa3 + s * Ht * At; sbl = 8; ncols = At; }
  else if (q < OC2) { mb = OC1; src = Wc1 + s * Dt * Ht; sbl = 7; ncols = Ht; }
  else              { mb = OC2; src = Wc2 + s * Ht * Ht; sbl = 8; ncols = Ht; }
  const int b = q - mb;
  const int n = b >> sbl;
  const int r = b & ((1 << sbl) - 1);
  const int k0 = (r ^ ((n & 7) << 4)) >> 1;   // XOR bits 4-6 keep 8B chunks intact
  us4 o;
#pragma unroll
  for (int j = 0; j < 4; ++j) {
    float f;
    if (ncols == At) f = (n < At) ? src[(k0 + j) * At + n] : 0.0f;  // pad A 17->32
    else             f = src[(k0 + j) * Ht + n];
    ((unsigned short*)&o)[j] = f2bf(f);
  }
  *reinterpret_cast<us4*>(G + s * SKB + q) = o;
}

// ---------- phase 3: fused per-skill actor+critic MLP ----------
__global__ __launch_bounds__(256, 3) void k_main(
    const float* __restrict__ obs,
    const float* __restrict__ ba1, const float* __restrict__ ba2,
    const float* __restrict__ ba3, const float* __restrict__ bc1,
    const float* __restrict__ bc2, const float* __restrict__ Wc3,
    const float* __restrict__ bc3,
    const int* __restrict__ cnt, const unsigned short* __restrict__ perm,
    const char* __restrict__ G, float* __restrict__ out) {
  __shared__ char wbuf[32768];   // largest weight image (Wa2/Wc2)
  __shared__ char hbuf[16384];   // 64 rows x 256B, XOR-swizzled bf16 activations
  __shared__ int pbuf[64];

  const int s = blockIdx.y;
  const int count = cnt[s];
  const int base = blockIdx.x * 64;
  if (base >= count) return;
  const int nrows = min(64, count - base);

  const int tid = threadIdx.x;
  const int wave = tid >> 6, lane = tid & 63;
  const int lr = lane & 15, lg = lane >> 4;

  if (tid < 64) pbuf[tid] = (tid < nrows) ? (int)perm[s * Bt + base + tid] : 0;

  const char* Gs = G + s * SKB;
  stageW(Gs + OA1, wbuf, 16384, wave, lane);
  __syncthreads();   // wbuf=Wa1 ready, pbuf ready

  // layer-1 A fragments from gathered obs rows (shared by actor & critic)
  const int myrow = pbuf[wave * 16 + lr];
  const float* ap = obs + myrow * Dt + lg * 8;
  f32x4 x0 = *(const f32x4*)(ap);
  f32x4 x1 = *(const f32x4*)(ap + 4);
  f32x4 x2 = *(const f32x4*)(ap + 32);
  f32x4 x3 = *(const f32x4*)(ap + 36);
  bf16x8 a0, a1;
#pragma unroll
  for (int j = 0; j < 4; ++j) {
    a0[j] = (short)f2bf(x0[j]); a0[4 + j] = (short)f2bf(x1[j]);
    a1[j] = (short)f2bf(x2[j]); a1[4 + j] = (short)f2bf(x3[j]);
  }

  const int hr = wave * 16 + lr;          // own LDS row for A-frag reads
  const int hsw = (hr & 7) << 4;
  const char* hrow = hbuf + hr * 256;

  // ================= actor layer 1 =================
#pragma unroll
  for (int nt = 0; nt < 8; ++nt) {
    const int n = nt * 16 + lr;
    const char* wrow = wbuf + n * 128;
    const int sw = (n & 7) << 4;
    bf16x8 b0 = *(const bf16x8*)(wrow + ((lg * 16) ^ sw));
    bf16x8 b1 = *(const bf16x8*)(wrow + ((64 + lg * 16) ^ sw));
    f32x4 acc = {0.f, 0.f, 0.f, 0.f};
    acc = MFMA(a0, b0, acc);
    acc = MFMA(a1, b1, acc);
    const float bias = ba1[s * Ht + n];
#pragma unroll
    for (int i = 0; i < 4; ++i) {
      const int row = wave * 16 + lg * 4 + i;   // C/D: col=lane&15, row=(lane>>4)*4+i
      *(unsigned short*)(hbuf + row * 256 + ((2 * n) ^ ((row & 7) << 4))) =
          f2bf(fast_tanh(acc[i] + bias));
    }
  }
  __syncthreads();
  stageW(Gs + OA2, wbuf, 32768, wave, lane);
  __syncthreads();

  // ================= actor layer 2 =================
  {
    bf16x8 A0 = *(const bf16x8*)(hrow + ((lg * 16) ^ hsw));
    bf16x8 A1 = *(const bf16x8*)(hrow + ((64 + lg * 16) ^ hsw));
    bf16x8 A2 = *(const bf16x8*)(hrow + ((128 + lg * 16) ^ hsw));
    bf16x8 A3 = *(const bf16x8*)(hrow + ((192 + lg * 16) ^ hsw));
#pragma unroll
    for (int nt = 0; nt < 8; ++nt) {
      const int n = nt * 16 + lr;
      const char* wrow = wbuf + n * 256;
      const int sw = (n & 7) << 4;
      f32x4 acc = {0.f, 0.f, 0.f, 0.f};
      acc = MFMA(A0, *(const bf16x8*)(wrow + ((lg * 16) ^ sw)), acc);
      acc = MFMA(A1, *(const bf16x8*)(wrow + ((64 + lg * 16) ^ sw)), acc);
      acc = MFMA(A2, *(const bf16x8*)(wrow + ((128 + lg * 16) ^ sw)), acc);
      acc = MFMA(A3, *(const bf16x8*)(wrow + ((192 + lg * 16) ^ sw)), acc);
      const float bias = ba2[s * Ht + n];
#pragma unroll
      for (int i = 0; i < 4; ++i) {
        const int row = wave * 16 + lg * 4 + i;   // own rows only: race-free
        *(unsigned short*)(hbuf + row * 256 + ((2 * n) ^ ((row & 7) << 4))) =
            f2bf(fast_tanh(acc[i] + bias));
      }
    }
  }
  __syncthreads();
  stageW(Gs + OA3, wbuf, 8192, wave, lane);
  __syncthreads();

  // ================= actor layer 3 -> logits =================
  {
    bf16x8 A0 = *(const bf16x8*)(hrow + ((lg * 16) ^ hsw));
    bf16x8 A1 = *(const bf16x8*)(hrow + ((64 + lg * 16) ^ hsw));
    bf16x8 A2 = *(const bf16x8*)(hrow + ((128 + lg * 16) ^ hsw));
    bf16x8 A3 = *(const bf16x8*)(hrow + ((192 + lg * 16) ^ hsw));
#pragma unroll
    for (int nt = 0; nt < 2; ++nt) {
      const int n = nt * 16 + lr;       // 0..31, cols >=17 are zero-padded weights
      const char* wrow = wbuf + n * 256;
      const int sw = (n & 7) << 4;
      f32x4 acc = {0.f, 0.f, 0.f, 0.f};
      acc = MFMA(A0, *(const bf16x8*)(wrow + ((lg * 16) ^ sw)), acc);
      acc = MFMA(A1, *(const bf16x8*)(wrow + ((64 + lg * 16) ^ sw)), acc);
      acc = MFMA(A2, *(const bf16x8*)(wrow + ((128 + lg * 16) ^ sw)), acc);
      acc = MFMA(A3, *(const bf16x8*)(wrow + ((192 + lg * 16) ^ sw)), acc);
      if (n < At) {
        const float bias = ba3[s * At + n];
#pragma unroll
        for (int i = 0; i < 4; ++i) {
          const int row = wave * 16 + lg * 4 + i;
          if (row < nrows) out[pbuf[row] * At + n] = acc[i] + bias;
        }
      }
    }
  }
  __syncthreads();
  stageW(Gs + OC1, wbuf, 16384, wave, lane);
  __syncthreads();

  // ================= critic layer 1 =================
#pragma unroll
  for (int nt = 0; nt < 8; ++nt) {
    const int n = nt * 16 + lr;
    const char* wrow = wbuf + n * 128;
    const int sw = (n & 7) << 4;
    bf16x8 b0 = *(const bf16x8*)(wrow + ((lg * 16) ^ sw));
    bf16x8 b1 = *(const bf16x8*)(wrow + ((64 + lg * 16) ^ sw));
    f32x4 acc = {0.f, 0.f, 0.f, 0.f};
    acc = MFMA(a0, b0, acc);
    acc = MFMA(a1, b1, acc);
    const float bias = bc1[s * Ht + n];
#pragma unroll
    for (int i = 0; i < 4; ++i) {
      const int row = wave * 16 + lg * 4 + i;
      *(unsigned short*)(hbuf + row * 256 + ((2 * n) ^ ((row & 7) << 4))) =
          f2bf(fast_tanh(acc[i] + bias));
    }
  }
  __syncthreads();
  stageW(Gs + OC2, wbuf, 32768, wave, lane);
  __syncthreads();

  // ================= critic layer 2 + value (in-register epilogue) =================
  {
    bf16x8 A0 = *(const bf16x8*)(hrow + ((lg * 16) ^ hsw));
    bf16x8 A1 = *(const bf16x8*)(hrow + ((64 + lg * 16) ^ hsw));
    bf16x8 A2 = *(const bf16x8*)(hrow + ((128 + lg * 16) ^ hsw));
    bf16x8 A3 = *(const bf16x8*)(hrow + ((192 + lg * 16) ^ hsw));
    float vp0 = 0.f, vp1 = 0.f, vp2 = 0.f, vp3 = 0.f;
#pragma unroll
    for (int nt = 0; nt < 8; ++nt) {
      const int n = nt * 16 + lr;
      const char* wrow = wbuf + n * 256;
      const int sw = (n & 7) << 4;
      f32x4 acc = {0.f, 0.f, 0.f, 0.f};
      acc = MFMA(A0, *(const bf16x8*)(wrow + ((lg * 16) ^ sw)), acc);
      acc = MFMA(A1, *(const bf16x8*)(wrow + ((64 + lg * 16) ^ sw)), acc);
      acc = MFMA(A2, *(const bf16x8*)(wrow + ((128 + lg * 16) ^ sw)), acc);
      acc = MFMA(A3, *(const bf16x8*)(wrow + ((192 + lg * 16) ^ sw)), acc);
      const float bias = bc2[s * Ht + n];
      const float w3 = Wc3[s * Ht + n];
      vp0 += fast_tanh(acc[0] + bias) * w3;
      vp1 += fast_tanh(acc[1] + bias) * w3;
      vp2 += fast_tanh(acc[2] + bias) * w3;
      vp3 += fast_tanh(acc[3] + bias) * w3;
    }
#pragma unroll
    for (int d = 1; d < 16; d <<= 1) {   // reduce over the 16 cols held per lane group
      vp0 += __shfl_xor(vp0, d);
      vp1 += __shfl_xor(vp1, d);
      vp2 += __shfl_xor(vp2, d);
      vp3 += __shfl_xor(vp3, d);
    }
    if (lr == 0) {
      const float b3 = bc3[s];
      const int r0 = wave * 16 + lg * 4;
      if (r0 + 0 < nrows) out[Bt * At + pbuf[r0 + 0]] = vp0 + b3;
      if (r0 + 1 < nrows) out[Bt * At + pbuf[r0 + 1]] = vp1 + b3;
      if (r0 + 2 < nrows) out[Bt * At + pbuf[r0 + 2]] = vp2 + b3;
      if (r0 + 3 < nrows) out[Bt * At + pbuf[r0 + 3]] = vp3 + b3;
    }
  }
}

extern "C" void kernel_launch(void* const* d_in, const int* in_sizes, int n_in,
                              void* d_out, int out_size, void* d_ws, size_t ws_size,
                              hipStream_t stream) {
  const float* obs = (const float*)d_in[0];
  const int* sid   = (const int*)d_in[1];
  const float* Wa1 = (const float*)d_in[2];
  const float* ba1 = (const float*)d_in[3];
  const float* Wa2 = (const float*)d_in[4];
  const float* ba2 = (const float*)d_in[5];
  const float* Wa3 = (const float*)d_in[6];
  const float* ba3 = (const float*)d_in[7];
  const float* Wc1 = (const float*)d_in[8];
  const float* bc1 = (const float*)d_in[9];
  const float* Wc2 = (const float*)d_in[10];
  const float* bc2 = (const float*)d_in[11];
  const float* Wc3 = (const float*)d_in[12];
  const float* bc3 = (const float*)d_in[13];
  float* out = (float*)d_out;
  char* ws = (char*)d_ws;

  int* cnt = (int*)(ws + CNT_OFF);
  unsigned short* perm = (unsigned short*)(ws + PERM_OFF);
  char* G = ws + WB_OFF;

  hipMemsetAsync(cnt, 0, St * sizeof(int), stream);
  k_bucket<<<dim3(Bt / 256), dim3(256), 0, stream>>>(sid, perm, cnt);
  k_prep<<<dim3(52, St), dim3(256), 0, stream>>>(Wa1, Wa2, Wa3, Wc1, Wc2, G);
  k_main<<<dim3(Bt / 64, St), dim3(256), 0, stream>>>(
      obs, ba1, ba2, ba3, bc1, bc2, Wc3, bc3, cnt, perm, G, out);
}